// Round 1
// baseline (439.763 us; speedup 1.0000x reference)
//
#include <hip/hip_runtime.h>
#include <hip/hip_bf16.h>

using short8 = __attribute__((ext_vector_type(8))) short;
using f32x4  = __attribute__((ext_vector_type(4))) float;

#define MFMA16(a,b,c) __builtin_amdgcn_mfma_f32_16x16x32_bf16(a,b,c,0,0,0)

__device__ __forceinline__ unsigned short bf16r(float f) {
  unsigned u = __builtin_bit_cast(unsigned, f);
  return (unsigned short)((u + 0x7fffu + ((u >> 16) & 1u)) >> 16);
}

constexpr int TB = 4;       // batch
constexpr int TT = 4096;    // seq len
constexpr int DM = 1024;    // d_model
constexpr int DD = 128;     // head dim
constexpr int NE = 384;     // 3*DD
constexpr float QSCALE = 0.12751744f;  // 128^-0.5 * log2(e)

// ---------------- kernel 0: W transpose + bf16 cast ----------------
// W [1024][384] f32 -> Wt [384][1024] bf16, so GEMM B-frags read contiguous k.
__global__ void wtrans_kernel(const float* __restrict__ W, unsigned short* __restrict__ Wt) {
  int i = blockIdx.x * 256 + threadIdx.x;   // 0 .. 1024*384-1
  int k = i / NE, n = i - k * NE;
  Wt[n * DM + k] = bf16r(W[i]);
}

// ---------------- kernel 1: QKV projection (LDS-free MFMA GEMM) ----------------
// grid 256 blocks (64 rows each), 4 waves/block, wave = 16 rows x 384 cols.
__global__ __launch_bounds__(256, 2)
void qkv_kernel(const float* __restrict__ x, const unsigned short* __restrict__ Wt,
                const float* __restrict__ bq,
                unsigned short* __restrict__ Qb, unsigned short* __restrict__ Kb,
                unsigned short* __restrict__ Vt) {
  const int tid = threadIdx.x;
  const int wid = tid >> 6, lane = tid & 63;
  const int g = lane >> 4, c = lane & 15;
  const int m0 = blockIdx.x * 64;
  const int arow = m0 + wid * 16 + c;       // A-frag: m = lane&15

  f32x4 acc[24];
  #pragma unroll
  for (int t = 0; t < 24; ++t) acc[t] = f32x4{0.f, 0.f, 0.f, 0.f};

  const float* xrow = x + (size_t)arow * DM + g * 8;

  for (int kb = 0; kb < DM / 32; ++kb) {
    f32x4 a0 = *(const f32x4*)(xrow + kb * 32);
    f32x4 a1 = *(const f32x4*)(xrow + kb * 32 + 4);
    short8 af;
    af[0] = (short)bf16r(a0[0]); af[1] = (short)bf16r(a0[1]);
    af[2] = (short)bf16r(a0[2]); af[3] = (short)bf16r(a0[3]);
    af[4] = (short)bf16r(a1[0]); af[5] = (short)bf16r(a1[1]);
    af[6] = (short)bf16r(a1[2]); af[7] = (short)bf16r(a1[3]);
    #pragma unroll
    for (int t = 0; t < 24; ++t) {
      short8 bf = *(const short8*)(Wt + (size_t)(t * 16 + c) * DM + kb * 32 + g * 8);
      acc[t] = MFMA16(af, bf, acc[t]);
    }
  }

  // epilogue: bias + de-interleave (col e: e%3==0 -> Q, 1 -> K, 2 -> V^T)
  #pragma unroll
  for (int t = 0; t < 24; ++t) {
    int e = t * 16 + c;
    float bias = bq[e];
    int n3 = e % 3, d = e / 3;
    #pragma unroll
    for (int r = 0; r < 4; ++r) {
      int row = m0 + wid * 16 + g * 4 + r;  // C/D: row=(l>>4)*4+r
      float val = acc[t][r] + bias;
      int bb = row >> 12, tr = row & (TT - 1);
      if (n3 == 0)      Qb[row * DD + d] = bf16r(val * QSCALE);
      else if (n3 == 1) Kb[row * DD + d] = bf16r(val);
      else              Vt[(bb * DD + d) * TT + tr] = bf16r(val);
    }
  }
}

// ---------------- kernel 2: flash attention ----------------
constexpr int KVB = 64;  // KV tile rows
__global__ __launch_bounds__(256, 2)
void attn_kernel(const unsigned short* __restrict__ Qb, const unsigned short* __restrict__ Kb,
                 const unsigned short* __restrict__ Vt, float* __restrict__ out) {
  const int tid = threadIdx.x;
  const int wid = tid >> 6, lane = tid & 63;
  const int g = lane >> 4, c = lane & 15;
  const int b = blockIdx.y;
  const int q0 = blockIdx.x * 64;

  __shared__ unsigned short Kt[KVB][DD + 8];       // 17408 B
  __shared__ unsigned short Vts[DD][KVB + 8];      // 18432 B (V^T tile)
  __shared__ unsigned short Pl[4][16][KVB + 8];    // 9216 B, per-wave P

  // Q fragments in registers (rows q0 + wid*16 + c), pre-scaled by QSCALE
  short8 qf[4];
  {
    const unsigned short* qrow = Qb + (size_t)(b * TT + q0 + wid * 16 + c) * DD + g * 8;
    #pragma unroll
    for (int kk = 0; kk < 4; ++kk) qf[kk] = *(const short8*)(qrow + kk * 32);
  }

  float mr[4], lr[4];
  #pragma unroll
  for (int r = 0; r < 4; ++r) { mr[r] = -1e30f; lr[r] = 0.f; }
  f32x4 oacc[8];
  #pragma unroll
  for (int n = 0; n < 8; ++n) oacc[n] = f32x4{0.f, 0.f, 0.f, 0.f};

  // staging registers (prefetch next KV tile while computing current)
  short8 kreg[4], vreg[4];
  const int krow_ = tid >> 4;          // 0..15 (16 thr/row, 8 el each)
  const int kcol_ = (tid & 15) * 8;
  const int vrow_ = tid >> 3;          // 0..31 (8 thr/row, 8 el each)
  const int vcol_ = (tid & 7) * 8;

  const unsigned short* Kbase = Kb + (size_t)(b * TT) * DD;
  const unsigned short* Vbase = Vt + (size_t)(b * DD) * TT;

  // prologue: stage tile 0
  #pragma unroll
  for (int p = 0; p < 4; ++p) {
    kreg[p] = *(const short8*)(Kbase + (size_t)(p * 16 + krow_) * DD + kcol_);
    vreg[p] = *(const short8*)(Vbase + (size_t)(p * 32 + vrow_) * TT + vcol_);
  }
  #pragma unroll
  for (int p = 0; p < 4; ++p) {
    *(short8*)&Kt[p * 16 + krow_][kcol_]  = kreg[p];
    *(short8*)&Vts[p * 32 + vrow_][vcol_] = vreg[p];
  }
  __syncthreads();

  const int NT = TT / KVB;   // 64
  for (int it = 0; it < NT; ++it) {
    // issue next tile's global loads early (latency hides under compute)
    if (it + 1 < NT) {
      int s0 = (it + 1) * KVB;
      #pragma unroll
      for (int p = 0; p < 4; ++p) {
        kreg[p] = *(const short8*)(Kbase + (size_t)(s0 + p * 16 + krow_) * DD + kcol_);
        vreg[p] = *(const short8*)(Vbase + (size_t)(p * 32 + vrow_) * TT + s0 + vcol_);
      }
    }

    // QK^T: S[16 q][64 keys] per wave
    f32x4 sacc[4];
    #pragma unroll
    for (int t = 0; t < 4; ++t) sacc[t] = f32x4{0.f, 0.f, 0.f, 0.f};
    #pragma unroll
    for (int kk = 0; kk < 4; ++kk) {
      #pragma unroll
      for (int t = 0; t < 4; ++t) {
        short8 kf = *(const short8*)&Kt[t * 16 + c][kk * 32 + g * 8];
        sacc[t] = MFMA16(qf[kk], kf, sacc[t]);
      }
    }

    // online softmax, log2 domain. Row r of lane = q-row g*4+r; 64 scores of a
    // q-row live in the 16 lanes sharing g (4 per lane, one per t).
    float pe[4][4];
    #pragma unroll
    for (int r = 0; r < 4; ++r) {
      float mx = fmaxf(fmaxf(sacc[0][r], sacc[1][r]), fmaxf(sacc[2][r], sacc[3][r]));
      mx = fmaxf(mx, __shfl_xor(mx, 1));
      mx = fmaxf(mx, __shfl_xor(mx, 2));
      mx = fmaxf(mx, __shfl_xor(mx, 4));
      mx = fmaxf(mx, __shfl_xor(mx, 8));
      float mnew = fmaxf(mr[r], mx);
      float alpha = exp2f(mr[r] - mnew);
      mr[r] = mnew;
      float ps = 0.f;
      #pragma unroll
      for (int t = 0; t < 4; ++t) { pe[t][r] = exp2f(sacc[t][r] - mnew); ps += pe[t][r]; }
      ps += __shfl_xor(ps, 1);
      ps += __shfl_xor(ps, 2);
      ps += __shfl_xor(ps, 4);
      ps += __shfl_xor(ps, 8);
      lr[r] = lr[r] * alpha + ps;
      #pragma unroll
      for (int n = 0; n < 8; ++n) oacc[n][r] *= alpha;
    }

    // P -> per-wave LDS (wave-synchronous, no barrier needed)
    #pragma unroll
    for (int t = 0; t < 4; ++t)
      #pragma unroll
      for (int r = 0; r < 4; ++r)
        Pl[wid][g * 4 + r][t * 16 + c] = bf16r(pe[t][r]);

    // PV: O[16 q][128 d] += P[16][64] @ V[64][128]
    #pragma unroll
    for (int ks = 0; ks < 2; ++ks) {
      short8 pf = *(const short8*)&Pl[wid][c][ks * 32 + g * 8];
      #pragma unroll
      for (int n = 0; n < 8; ++n) {
        short8 vf = *(const short8*)&Vts[n * 16 + c][ks * 32 + g * 8];
        oacc[n] = MFMA16(pf, vf, oacc[n]);
      }
    }

    __syncthreads();   // all waves done reading Kt/Vts
    if (it + 1 < NT) {
      #pragma unroll
      for (int p2 = 0; p2 < 4; ++p2) {
        *(short8*)&Kt[p2 * 16 + krow_][kcol_]  = kreg[p2];
        *(short8*)&Vts[p2 * 32 + vrow_][vcol_] = vreg[p2];
      }
    }
    __syncthreads();   // staged tile visible
  }

  // epilogue: normalize and store fp32
  float inv[4];
  #pragma unroll
  for (int r = 0; r < 4; ++r) inv[r] = 1.0f / lr[r];
  #pragma unroll
  for (int n = 0; n < 8; ++n) {
    #pragma unroll
    for (int r = 0; r < 4; ++r) {
      int row = q0 + wid * 16 + g * 4 + r;
      out[(size_t)(b * TT + row) * DD + n * 16 + c] = oacc[n][r] * inv[r];
    }
  }
}

extern "C" void kernel_launch(void* const* d_in, const int* in_sizes, int n_in,
                              void* d_out, int out_size, void* d_ws, size_t ws_size,
                              hipStream_t stream) {
  const float* x  = (const float*)d_in[0];   // [4,4096,1024]
  const float* W  = (const float*)d_in[1];   // [1024,384]
  const float* bq = (const float*)d_in[2];   // [384]
  float* out = (float*)d_out;                // [4,4096,128] f32

  unsigned char* ws = (unsigned char*)d_ws;
  unsigned short* Qb = (unsigned short*)(ws);                  // [4][4096][128] bf16 (scaled)
  unsigned short* Kb = (unsigned short*)(ws + (4u  << 20));    // [4][4096][128] bf16
  unsigned short* Vt = (unsigned short*)(ws + (8u  << 20));    // [4][128][4096] bf16 (V^T)
  unsigned short* Wt = (unsigned short*)(ws + (12u << 20));    // [384][1024] bf16

  wtrans_kernel<<<(DM * NE) / 256, 256, 0, stream>>>(W, Wt);
  qkv_kernel<<<TB * TT / 64, 256, 0, stream>>>(x, Wt, bq, Qb, Kb, Vt);
  attn_kernel<<<dim3(TT / 64, TB), 256, 0, stream>>>(Qb, Kb, Vt, out);
}

// Round 2
// 318.398 us; speedup vs baseline: 1.3812x; 1.3812x over previous
//
#include <hip/hip_runtime.h>
#include <hip/hip_bf16.h>

using short8 = __attribute__((ext_vector_type(8))) short;
using f32x4  = __attribute__((ext_vector_type(4))) float;

#define MFMA16(a,b,c) __builtin_amdgcn_mfma_f32_16x16x32_bf16(a,b,c,0,0,0)

__device__ __forceinline__ unsigned short bf16r(float f) {
  unsigned u = __builtin_bit_cast(unsigned, f);
  return (unsigned short)((u + 0x7fffu + ((u >> 16) & 1u)) >> 16);
}

constexpr int TB = 4;       // batch
constexpr int TT = 4096;    // seq len
constexpr int DM = 1024;    // d_model
constexpr int DD = 128;     // head dim
constexpr int NE = 384;     // 3*DD
constexpr int NSPLIT = 4;   // flash-decode KV split
constexpr int CHUNK = TT / NSPLIT;  // 1024
constexpr float QSCALE = 0.12751744f;  // 128^-0.5 * log2(e)

// ---------------- kernel 0: W transpose + bf16 cast ----------------
__global__ void wtrans_kernel(const float* __restrict__ W, unsigned short* __restrict__ Wt) {
  int i = blockIdx.x * 256 + threadIdx.x;   // 0 .. 1024*384-1
  int k = i / NE, n = i - k * NE;
  Wt[n * DM + k] = bf16r(W[i]);
}

// ---------------- kernel 1: QKV projection ----------------
// 1024 blocks x 16 rows; 4 waves/block each own 6 of 24 column-frags (96 cols).
// B-frags from global (Wt is L2-resident, 768 KB). 16 waves/CU hides latency.
__global__ __launch_bounds__(256, 4)
void qkv_kernel(const float* __restrict__ x, const unsigned short* __restrict__ Wt,
                const float* __restrict__ bq,
                unsigned short* __restrict__ Qb, unsigned short* __restrict__ Kb,
                unsigned short* __restrict__ Vt) {
  const int tid = threadIdx.x;
  const int wid = tid >> 6, lane = tid & 63;
  const int g = lane >> 4, c = lane & 15;
  const int m0 = blockIdx.x * 16;
  const int t0 = wid * 6;

  f32x4 acc[6];
  #pragma unroll
  for (int j = 0; j < 6; ++j) acc[j] = f32x4{0.f, 0.f, 0.f, 0.f};

  const float* xrow = x + (size_t)(m0 + c) * DM + g * 8;

  for (int kb = 0; kb < DM / 32; ++kb) {
    f32x4 a0 = *(const f32x4*)(xrow + kb * 32);
    f32x4 a1 = *(const f32x4*)(xrow + kb * 32 + 4);
    short8 af;
    af[0] = (short)bf16r(a0[0]); af[1] = (short)bf16r(a0[1]);
    af[2] = (short)bf16r(a0[2]); af[3] = (short)bf16r(a0[3]);
    af[4] = (short)bf16r(a1[0]); af[5] = (short)bf16r(a1[1]);
    af[6] = (short)bf16r(a1[2]); af[7] = (short)bf16r(a1[3]);
    #pragma unroll
    for (int j = 0; j < 6; ++j) {
      short8 bf = *(const short8*)(Wt + (size_t)((t0 + j) * 16 + c) * DM + kb * 32 + g * 8);
      acc[j] = MFMA16(af, bf, acc[j]);
    }
  }

  #pragma unroll
  for (int j = 0; j < 6; ++j) {
    int e = (t0 + j) * 16 + c;
    float bias = bq[e];
    int n3 = e % 3, d = e / 3;
    #pragma unroll
    for (int r = 0; r < 4; ++r) {
      int row = m0 + g * 4 + r;            // C/D: row=(l>>4)*4+r, col=l&15
      float val = acc[j][r] + bias;
      int bb = row >> 12, tr = row & (TT - 1);
      if (n3 == 0)      Qb[row * DD + d] = bf16r(val * QSCALE);
      else if (n3 == 1) Kb[row * DD + d] = bf16r(val);
      else              Vt[(bb * DD + d) * TT + tr] = bf16r(val);
    }
  }
}

// ---------------- kernel 2: flash attention, KV-split partials ----------------
constexpr int KVB = 64;
__global__ __launch_bounds__(256, 3)
void attn_kernel(const unsigned short* __restrict__ Qb, const unsigned short* __restrict__ Kb,
                 const unsigned short* __restrict__ Vt,
                 float* __restrict__ Opart, float* __restrict__ Mpart, float* __restrict__ Lpart) {
  const int tid = threadIdx.x;
  const int wid = tid >> 6, lane = tid & 63;
  const int g = lane >> 4, c = lane & 15;
  const int b = blockIdx.y;
  const int z = blockIdx.z;
  const int q0 = blockIdx.x * 64;
  const int s_base = z * CHUNK;

  __shared__ unsigned short Kt[KVB][DD + 8];
  __shared__ unsigned short Vts[DD][KVB + 8];
  __shared__ unsigned short Pl[4][16][KVB + 8];

  short8 qf[4];
  {
    const unsigned short* qrow = Qb + (size_t)(b * TT + q0 + wid * 16 + c) * DD + g * 8;
    #pragma unroll
    for (int kk = 0; kk < 4; ++kk) qf[kk] = *(const short8*)(qrow + kk * 32);
  }

  float mr[4], lr[4];
  #pragma unroll
  for (int r = 0; r < 4; ++r) { mr[r] = -1e30f; lr[r] = 0.f; }
  f32x4 oacc[8];
  #pragma unroll
  for (int n = 0; n < 8; ++n) oacc[n] = f32x4{0.f, 0.f, 0.f, 0.f};

  short8 kreg[4], vreg[4];
  const int krow_ = tid >> 4;
  const int kcol_ = (tid & 15) * 8;
  const int vrow_ = tid >> 3;
  const int vcol_ = (tid & 7) * 8;

  const unsigned short* Kbase = Kb + (size_t)(b * TT) * DD;
  const unsigned short* Vbase = Vt + (size_t)(b * DD) * TT;

  #pragma unroll
  for (int p = 0; p < 4; ++p) {
    kreg[p] = *(const short8*)(Kbase + (size_t)(s_base + p * 16 + krow_) * DD + kcol_);
    vreg[p] = *(const short8*)(Vbase + (size_t)(p * 32 + vrow_) * TT + s_base + vcol_);
  }
  #pragma unroll
  for (int p = 0; p < 4; ++p) {
    *(short8*)&Kt[p * 16 + krow_][kcol_]  = kreg[p];
    *(short8*)&Vts[p * 32 + vrow_][vcol_] = vreg[p];
  }
  __syncthreads();

  const int NT = CHUNK / KVB;   // 16
  for (int it = 0; it < NT; ++it) {
    if (it + 1 < NT) {
      int s0 = s_base + (it + 1) * KVB;
      #pragma unroll
      for (int p = 0; p < 4; ++p) {
        kreg[p] = *(const short8*)(Kbase + (size_t)(s0 + p * 16 + krow_) * DD + kcol_);
        vreg[p] = *(const short8*)(Vbase + (size_t)(p * 32 + vrow_) * TT + s0 + vcol_);
      }
    }

    f32x4 sacc[4];
    #pragma unroll
    for (int t = 0; t < 4; ++t) sacc[t] = f32x4{0.f, 0.f, 0.f, 0.f};
    #pragma unroll
    for (int kk = 0; kk < 4; ++kk) {
      #pragma unroll
      for (int t = 0; t < 4; ++t) {
        short8 kf = *(const short8*)&Kt[t * 16 + c][kk * 32 + g * 8];
        sacc[t] = MFMA16(qf[kk], kf, sacc[t]);
      }
    }

    float pe[4][4];
    #pragma unroll
    for (int r = 0; r < 4; ++r) {
      float mx = fmaxf(fmaxf(sacc[0][r], sacc[1][r]), fmaxf(sacc[2][r], sacc[3][r]));
      mx = fmaxf(mx, __shfl_xor(mx, 1));
      mx = fmaxf(mx, __shfl_xor(mx, 2));
      mx = fmaxf(mx, __shfl_xor(mx, 4));
      mx = fmaxf(mx, __shfl_xor(mx, 8));
      float mnew = fmaxf(mr[r], mx);
      float alpha = exp2f(mr[r] - mnew);
      mr[r] = mnew;
      float ps = 0.f;
      #pragma unroll
      for (int t = 0; t < 4; ++t) { pe[t][r] = exp2f(sacc[t][r] - mnew); ps += pe[t][r]; }
      ps += __shfl_xor(ps, 1);
      ps += __shfl_xor(ps, 2);
      ps += __shfl_xor(ps, 4);
      ps += __shfl_xor(ps, 8);
      lr[r] = lr[r] * alpha + ps;
      #pragma unroll
      for (int n = 0; n < 8; ++n) oacc[n][r] *= alpha;
    }

    #pragma unroll
    for (int t = 0; t < 4; ++t)
      #pragma unroll
      for (int r = 0; r < 4; ++r)
        Pl[wid][g * 4 + r][t * 16 + c] = bf16r(pe[t][r]);

    #pragma unroll
    for (int ks = 0; ks < 2; ++ks) {
      short8 pf = *(const short8*)&Pl[wid][c][ks * 32 + g * 8];
      #pragma unroll
      for (int n = 0; n < 8; ++n) {
        short8 vf = *(const short8*)&Vts[n * 16 + c][ks * 32 + g * 8];
        oacc[n] = MFMA16(pf, vf, oacc[n]);
      }
    }

    __syncthreads();
    if (it + 1 < NT) {
      #pragma unroll
      for (int p2 = 0; p2 < 4; ++p2) {
        *(short8*)&Kt[p2 * 16 + krow_][kcol_]  = kreg[p2];
        *(short8*)&Vts[p2 * 32 + vrow_][vcol_] = vreg[p2];
      }
    }
    __syncthreads();
  }

  // store unnormalized partials + (m,l) per row
  const size_t pbase = (size_t)(z * TB + b) * TT;
  #pragma unroll
  for (int n = 0; n < 8; ++n)
    #pragma unroll
    for (int r = 0; r < 4; ++r) {
      int row = q0 + wid * 16 + g * 4 + r;
      Opart[(pbase + row) * DD + n * 16 + c] = oacc[n][r];
    }
  if (c == 0) {
    #pragma unroll
    for (int r = 0; r < 4; ++r) {
      int row = q0 + wid * 16 + g * 4 + r;
      Mpart[pbase + row] = mr[r];
      Lpart[pbase + row] = lr[r];
    }
  }
}

// ---------------- kernel 3: split merge ----------------
__global__ void merge_kernel(const float* __restrict__ Opart, const float* __restrict__ Mpart,
                             const float* __restrict__ Lpart, float* __restrict__ out) {
  int i = blockIdx.x * 256 + threadIdx.x;   // 0 .. 16384*32-1
  int grow = i >> 5, d4 = (i & 31) << 2;
  float m[NSPLIT];
  float ms = -1e30f;
  #pragma unroll
  for (int s = 0; s < NSPLIT; ++s) { m[s] = Mpart[s * (TB * TT) + grow]; ms = fmaxf(ms, m[s]); }
  float w[NSPLIT];
  float denom = 0.f;
  #pragma unroll
  for (int s = 0; s < NSPLIT; ++s) {
    w[s] = exp2f(m[s] - ms);
    denom += w[s] * Lpart[s * (TB * TT) + grow];
  }
  float rd = 1.0f / denom;
  f32x4 o = {0.f, 0.f, 0.f, 0.f};
  #pragma unroll
  for (int s = 0; s < NSPLIT; ++s) {
    f32x4 v = *(const f32x4*)(Opart + (size_t)(s * (TB * TT) + grow) * DD + d4);
    o += v * w[s];
  }
  *(f32x4*)(out + (size_t)grow * DD + d4) = o * rd;
}

extern "C" void kernel_launch(void* const* d_in, const int* in_sizes, int n_in,
                              void* d_out, int out_size, void* d_ws, size_t ws_size,
                              hipStream_t stream) {
  const float* x  = (const float*)d_in[0];   // [4,4096,1024]
  const float* W  = (const float*)d_in[1];   // [1024,384]
  const float* bq = (const float*)d_in[2];   // [384]
  float* out = (float*)d_out;                // [4,4096,128] f32

  unsigned char* ws = (unsigned char*)d_ws;
  unsigned short* Qb = (unsigned short*)(ws);                  // 4 MB bf16 (scaled)
  unsigned short* Kb = (unsigned short*)(ws + (4u  << 20));    // 4 MB bf16
  unsigned short* Vt = (unsigned short*)(ws + (8u  << 20));    // 4 MB bf16 (V^T)
  unsigned short* Wt = (unsigned short*)(ws + (12u << 20));    // 768 KB bf16
  float* Mpart = (float*)(ws + (13u << 20));                   // 256 KB
  float* Lpart = (float*)(ws + (14u << 20));                   // 256 KB
  float* Opart = (float*)(ws + (16u << 20));                   // 32 MB

  wtrans_kernel<<<(DM * NE) / 256, 256, 0, stream>>>(W, Wt);
  qkv_kernel<<<TB * TT / 16, 256, 0, stream>>>(x, Wt, bq, Qb, Kb, Vt);
  attn_kernel<<<dim3(TT / 64, TB, NSPLIT), 256, 0, stream>>>(Qb, Kb, Vt, Opart, Mpart, Lpart);
  merge_kernel<<<(TB * TT * 32) / 256, 256, 0, stream>>>(Opart, Mpart, Lpart, out);
}

// Round 4
// 244.470 us; speedup vs baseline: 1.7988x; 1.3024x over previous
//
#include <hip/hip_runtime.h>
#include <hip/hip_bf16.h>

using short8 = __attribute__((ext_vector_type(8))) short;
using f32x4  = __attribute__((ext_vector_type(4))) float;

#define MFMA16(a,b,c) __builtin_amdgcn_mfma_f32_16x16x32_bf16(a,b,c,0,0,0)

__device__ __forceinline__ unsigned short bf16r(float f) {
  unsigned u = __builtin_bit_cast(unsigned, f);
  return (unsigned short)((u + 0x7fffu + ((u >> 16) & 1u)) >> 16);
}

// packed f32x8 -> bf16x8 via v_cvt_pk_bf16_f32 (RNE, same as bf16r)
__device__ __forceinline__ short8 cvt8(f32x4 lo, f32x4 hi) {
  union { short8 s; unsigned u[4]; } v;
  asm("v_cvt_pk_bf16_f32 %0, %1, %2" : "=v"(v.u[0]) : "v"(lo[0]), "v"(lo[1]));
  asm("v_cvt_pk_bf16_f32 %0, %1, %2" : "=v"(v.u[1]) : "v"(lo[2]), "v"(lo[3]));
  asm("v_cvt_pk_bf16_f32 %0, %1, %2" : "=v"(v.u[2]) : "v"(hi[0]), "v"(hi[1]));
  asm("v_cvt_pk_bf16_f32 %0, %1, %2" : "=v"(v.u[3]) : "v"(hi[2]), "v"(hi[3]));
  return v.s;
}

template <typename T>
__device__ __forceinline__ void load_lds16(const T* g, T* l) {
  __builtin_amdgcn_global_load_lds((const __attribute__((address_space(1))) unsigned*)g,
                                   (__attribute__((address_space(3))) unsigned*)l, 16, 0, 0);
}

constexpr int TB = 4;       // batch
constexpr int TT = 4096;    // seq len
constexpr int DM = 1024;    // d_model
constexpr int DD = 128;     // head dim
constexpr int NE = 384;     // 3*DD
constexpr int NSPLIT = 4;   // flash-decode KV split
constexpr int CHUNK = TT / NSPLIT;  // 1024
constexpr float QSCALE = 0.12751744f;  // 128^-0.5 * log2(e)

// ---------------- kernel 0: W transpose + bf16 cast ----------------
__global__ void wtrans_kernel(const float* __restrict__ W, unsigned short* __restrict__ Wt) {
  int i = blockIdx.x * 256 + threadIdx.x;   // 0 .. 1024*384-1
  int k = i / NE, n = i - k * NE;
  Wt[n * DM + k] = bf16r(W[i]);
}

// ---------------- kernel 1: QKV projection (m97-style 2-phase LDS GEMM) ----
// 128x128 tile, BK=32, 4 waves in 2x2 quadrants of 64x64, global_load_lds
// double-buffer; A staged fp32 and converted in-register via v_cvt_pk.
__global__ __launch_bounds__(256, 2)
void qkv_kernel(const float* __restrict__ x, const unsigned short* __restrict__ Wt,
                const float* __restrict__ bq,
                unsigned short* __restrict__ Qb, unsigned short* __restrict__ Kb,
                unsigned short* __restrict__ Vt) {
  const int tid = threadIdx.x;
  const int wid = tid >> 6, lane = tid & 63;
  const int g = lane >> 4, c = lane & 15;
  const int wr = wid >> 1, wc = wid & 1;
  const int m0 = blockIdx.x * 128;
  const int n0 = blockIdx.y * 128;

  // [k-slot][row][16B] layouts: frag reads are stride-16B across lanes -> b128 floor
  __shared__ float          As[2][8][128][4];   // 2 x 16 KB (fp32 A tile, BK=32)
  __shared__ unsigned short Bs[2][4][128][8];   // 2 x 8 KB  (bf16 B tile)

  f32x4 acc[4][4];
  #pragma unroll
  for (int m = 0; m < 4; ++m)
    #pragma unroll
    for (int n = 0; n < 4; ++n) acc[m][n] = f32x4{0.f, 0.f, 0.f, 0.f};

#define QKV_STAGE(buf, kb) do {                                                   \
    _Pragma("unroll")                                                             \
    for (int i_ = 0; i_ < 4; ++i_) {                                              \
      int L = i_ * 256 + tid, s_ = L >> 7, row_ = L & 127;                        \
      load_lds16(x + (size_t)(m0 + row_) * DM + (kb) * 32 + s_ * 4,               \
                 &As[buf][s_][row_][0]);                                          \
    }                                                                             \
    _Pragma("unroll")                                                             \
    for (int i_ = 0; i_ < 2; ++i_) {                                              \
      int L = i_ * 256 + tid, kk_ = L >> 7, col_ = L & 127;                       \
      load_lds16(Wt + (size_t)(n0 + col_) * DM + (kb) * 32 + kk_ * 8,             \
                 &Bs[buf][kk_][col_][0]);                                         \
    }                                                                             \
  } while (0)

  QKV_STAGE(0, 0);
  __syncthreads();

  for (int kb = 0; kb < DM / 32; ++kb) {
    const int cur = kb & 1;
    if (kb + 1 < DM / 32) QKV_STAGE(cur ^ 1, kb + 1);

    short8 a[4], b[4];
    #pragma unroll
    for (int m = 0; m < 4; ++m) {
      int row = wr * 64 + m * 16 + c;
      f32x4 lo = *(const f32x4*)&As[cur][g * 2][row][0];
      f32x4 hi = *(const f32x4*)&As[cur][g * 2 + 1][row][0];
      a[m] = cvt8(lo, hi);
    }
    #pragma unroll
    for (int n = 0; n < 4; ++n)
      b[n] = *(const short8*)&Bs[cur][g][wc * 64 + n * 16 + c][0];

    __builtin_amdgcn_s_setprio(1);
    #pragma unroll
    for (int m = 0; m < 4; ++m)
      #pragma unroll
      for (int n = 0; n < 4; ++n)
        acc[m][n] = MFMA16(a[m], b[n], acc[m][n]);
    __builtin_amdgcn_s_setprio(0);

    __syncthreads();   // waves done reading cur; staged cur^1 landed
  }

  // epilogue: bias + de-interleave (col e%3: 0->Q(scaled), 1->K, 2->V^T)
  #pragma unroll
  for (int n = 0; n < 4; ++n) {
    int e = n0 + wc * 64 + n * 16 + c;
    float bias = bq[e];
    int n3 = e % 3, d = e / 3;
    #pragma unroll
    for (int m = 0; m < 4; ++m) {
      #pragma unroll
      for (int r = 0; r < 4; ++r) {
        int row = m0 + wr * 64 + m * 16 + g * 4 + r;   // C/D: row=(l>>4)*4+r
        float val = acc[m][n][r] + bias;
        int bb = row >> 12, tr = row & (TT - 1);
        if (n3 == 0)      Qb[row * DD + d] = bf16r(val * QSCALE);
        else if (n3 == 1) Kb[row * DD + d] = bf16r(val);
        else              Vt[(bb * DD + d) * TT + tr] = bf16r(val);
      }
    }
  }
#undef QKV_STAGE
}

// ---------------- kernel 2: flash attention, KV-split partials ----------------
constexpr int KVB = 64;
__global__ __launch_bounds__(256, 3)
void attn_kernel(const unsigned short* __restrict__ Qb, const unsigned short* __restrict__ Kb,
                 const unsigned short* __restrict__ Vt,
                 float* __restrict__ Opart, float* __restrict__ Mpart, float* __restrict__ Lpart) {
  const int tid = threadIdx.x;
  const int wid = tid >> 6, lane = tid & 63;
  const int g = lane >> 4, c = lane & 15;
  const int b = blockIdx.y;
  const int z = blockIdx.z;
  const int q0 = blockIdx.x * 64;
  const int s_base = z * CHUNK;

  __shared__ unsigned short Kt[KVB][DD + 8];
  __shared__ unsigned short Vts[DD][KVB + 8];
  __shared__ unsigned short Pl[4][16][KVB + 8];

  short8 qf[4];
  {
    const unsigned short* qrow = Qb + (size_t)(b * TT + q0 + wid * 16 + c) * DD + g * 8;
    #pragma unroll
    for (int kk = 0; kk < 4; ++kk) qf[kk] = *(const short8*)(qrow + kk * 32);
  }

  short8 onesb;           // bf16 1.0 x8 : PV ones-column computes row-sum l via MFMA
  #pragma unroll
  for (int j = 0; j < 8; ++j) onesb[j] = (short)0x3F80;

  float mr[4];
  #pragma unroll
  for (int r = 0; r < 4; ++r) mr[r] = -1e30f;
  f32x4 lacc = f32x4{0.f, 0.f, 0.f, 0.f};
  f32x4 oacc[8];
  #pragma unroll
  for (int n = 0; n < 8; ++n) oacc[n] = f32x4{0.f, 0.f, 0.f, 0.f};

  short8 kreg[4], vreg[4];
  const int krow_ = tid >> 4;
  const int kcol_ = (tid & 15) * 8;
  const int vrow_ = tid >> 3;
  const int vcol_ = (tid & 7) * 8;

  const unsigned short* Kbase = Kb + (size_t)(b * TT) * DD;
  const unsigned short* Vbase = Vt + (size_t)(b * DD) * TT;

  #pragma unroll
  for (int p = 0; p < 4; ++p) {
    kreg[p] = *(const short8*)(Kbase + (size_t)(s_base + p * 16 + krow_) * DD + kcol_);
    vreg[p] = *(const short8*)(Vbase + (size_t)(p * 32 + vrow_) * TT + s_base + vcol_);
  }
  #pragma unroll
  for (int p = 0; p < 4; ++p) {
    *(short8*)&Kt[p * 16 + krow_][kcol_]  = kreg[p];
    *(short8*)&Vts[p * 32 + vrow_][vcol_] = vreg[p];
  }
  __syncthreads();

  const int NT = CHUNK / KVB;   // 16
  for (int it = 0; it < NT; ++it) {
    if (it + 1 < NT) {
      int s0 = s_base + (it + 1) * KVB;
      #pragma unroll
      for (int p = 0; p < 4; ++p) {
        kreg[p] = *(const short8*)(Kbase + (size_t)(s0 + p * 16 + krow_) * DD + kcol_);
        vreg[p] = *(const short8*)(Vbase + (size_t)(p * 32 + vrow_) * TT + s0 + vcol_);
      }
    }

    f32x4 sacc[4];
    #pragma unroll
    for (int t = 0; t < 4; ++t) sacc[t] = f32x4{0.f, 0.f, 0.f, 0.f};
    __builtin_amdgcn_s_setprio(1);
    #pragma unroll
    for (int kk = 0; kk < 4; ++kk) {
      #pragma unroll
      for (int t = 0; t < 4; ++t) {
        short8 kf = *(const short8*)&Kt[t * 16 + c][kk * 32 + g * 8];
        sacc[t] = MFMA16(qf[kk], kf, sacc[t]);
      }
    }
    __builtin_amdgcn_s_setprio(0);

    // online softmax (log2 domain); row-sum l comes from the PV ones-column MFMA
    float pe[4][4];
    #pragma unroll
    for (int r = 0; r < 4; ++r) {
      float mx = fmaxf(fmaxf(sacc[0][r], sacc[1][r]), fmaxf(sacc[2][r], sacc[3][r]));
      mx = fmaxf(mx, __shfl_xor(mx, 1));
      mx = fmaxf(mx, __shfl_xor(mx, 2));
      mx = fmaxf(mx, __shfl_xor(mx, 4));
      mx = fmaxf(mx, __shfl_xor(mx, 8));
      float mnew = fmaxf(mr[r], mx);
      float alpha = exp2f(mr[r] - mnew);
      mr[r] = mnew;
      #pragma unroll
      for (int t = 0; t < 4; ++t) pe[t][r] = exp2f(sacc[t][r] - mnew);
      lacc[r] *= alpha;
      #pragma unroll
      for (int n = 0; n < 8; ++n) oacc[n][r] *= alpha;
    }

    #pragma unroll
    for (int t = 0; t < 4; ++t)
      #pragma unroll
      for (int r = 0; r < 4; ++r)
        Pl[wid][g * 4 + r][t * 16 + c] = bf16r(pe[t][r]);

    __builtin_amdgcn_s_setprio(1);
    #pragma unroll
    for (int ks = 0; ks < 2; ++ks) {
      short8 pf = *(const short8*)&Pl[wid][c][ks * 32 + g * 8];
      lacc = MFMA16(pf, onesb, lacc);
      #pragma unroll
      for (int n = 0; n < 8; ++n) {
        short8 vf = *(const short8*)&Vts[n * 16 + c][ks * 32 + g * 8];
        oacc[n] = MFMA16(pf, vf, oacc[n]);
      }
    }
    __builtin_amdgcn_s_setprio(0);

    __syncthreads();
    if (it + 1 < NT) {
      #pragma unroll
      for (int p2 = 0; p2 < 4; ++p2) {
        *(short8*)&Kt[p2 * 16 + krow_][kcol_]  = kreg[p2];
        *(short8*)&Vts[p2 * 32 + vrow_][vcol_] = vreg[p2];
      }
    }
    __syncthreads();
  }

  const size_t pbase = (size_t)(z * TB + b) * TT;
  #pragma unroll
  for (int n = 0; n < 8; ++n)
    #pragma unroll
    for (int r = 0; r < 4; ++r) {
      int row = q0 + wid * 16 + g * 4 + r;
      Opart[(pbase + row) * DD + n * 16 + c] = oacc[n][r];
    }
  if (c == 0) {
    #pragma unroll
    for (int r = 0; r < 4; ++r) {
      int row = q0 + wid * 16 + g * 4 + r;
      Mpart[pbase + row] = mr[r];
      Lpart[pbase + row] = lacc[r];
    }
  }
}

// ---------------- kernel 3: split merge ----------------
__global__ void merge_kernel(const float* __restrict__ Opart, const float* __restrict__ Mpart,
                             const float* __restrict__ Lpart, float* __restrict__ out) {
  int i = blockIdx.x * 256 + threadIdx.x;   // 0 .. 16384*32-1
  int grow = i >> 5, d4 = (i & 31) << 2;
  float m[NSPLIT];
  float ms = -1e30f;
  #pragma unroll
  for (int s = 0; s < NSPLIT; ++s) { m[s] = Mpart[s * (TB * TT) + grow]; ms = fmaxf(ms, m[s]); }
  float w[NSPLIT];
  float denom = 0.f;
  #pragma unroll
  for (int s = 0; s < NSPLIT; ++s) {
    w[s] = exp2f(m[s] - ms);
    denom += w[s] * Lpart[s * (TB * TT) + grow];
  }
  float rd = 1.0f / denom;
  f32x4 o = {0.f, 0.f, 0.f, 0.f};
  #pragma unroll
  for (int s = 0; s < NSPLIT; ++s) {
    f32x4 v = *(const f32x4*)(Opart + (size_t)(s * (TB * TT) + grow) * DD + d4);
    o += v * w[s];
  }
  *(f32x4*)(out + (size_t)grow * DD + d4) = o * rd;
}

extern "C" void kernel_launch(void* const* d_in, const int* in_sizes, int n_in,
                              void* d_out, int out_size, void* d_ws, size_t ws_size,
                              hipStream_t stream) {
  const float* x  = (const float*)d_in[0];   // [4,4096,1024]
  const float* W  = (const float*)d_in[1];   // [1024,384]
  const float* bq = (const float*)d_in[2];   // [384]
  float* out = (float*)d_out;                // [4,4096,128] f32

  unsigned char* ws = (unsigned char*)d_ws;
  unsigned short* Qb = (unsigned short*)(ws);                  // 4 MB bf16 (scaled)
  unsigned short* Kb = (unsigned short*)(ws + (4u  << 20));    // 4 MB bf16
  unsigned short* Vt = (unsigned short*)(ws + (8u  << 20));    // 4 MB bf16 (V^T)
  unsigned short* Wt = (unsigned short*)(ws + (12u << 20));    // 768 KB bf16
  float* Mpart = (float*)(ws + (13u << 20));                   // 256 KB
  float* Lpart = (float*)(ws + (14u << 20));                   // 256 KB
  float* Opart = (float*)(ws + (16u << 20));                   // 32 MB

  wtrans_kernel<<<(DM * NE) / 256, 256, 0, stream>>>(W, Wt);
  qkv_kernel<<<dim3(TT * TB / 128, NE / 128), 256, 0, stream>>>(x, Wt, bq, Qb, Kb, Vt);
  attn_kernel<<<dim3(TT / 64, TB, NSPLIT), 256, 0, stream>>>(Qb, Kb, Vt, Opart, Mpart, Lpart);
  merge_kernel<<<(TB * TT * 32) / 256, 256, 0, stream>>>(Opart, Mpart, Lpart, out);
}

// Round 5
// 211.989 us; speedup vs baseline: 2.0745x; 1.1532x over previous
//
#include <hip/hip_runtime.h>
#include <hip/hip_bf16.h>

using short8 = __attribute__((ext_vector_type(8))) short;
using f32x4  = __attribute__((ext_vector_type(4))) float;

#define MFMA16(a,b,c) __builtin_amdgcn_mfma_f32_16x16x32_bf16(a,b,c,0,0,0)

__device__ __forceinline__ unsigned short bf16r(float f) {
  unsigned u = __builtin_bit_cast(unsigned, f);
  return (unsigned short)((u + 0x7fffu + ((u >> 16) & 1u)) >> 16);
}

// packed f32x8 -> bf16x8 via v_cvt_pk_bf16_f32 (RNE, same as bf16r)
__device__ __forceinline__ short8 cvt8(f32x4 lo, f32x4 hi) {
  union { short8 s; unsigned u[4]; } v;
  asm("v_cvt_pk_bf16_f32 %0, %1, %2" : "=v"(v.u[0]) : "v"(lo[0]), "v"(lo[1]));
  asm("v_cvt_pk_bf16_f32 %0, %1, %2" : "=v"(v.u[1]) : "v"(lo[2]), "v"(lo[3]));
  asm("v_cvt_pk_bf16_f32 %0, %1, %2" : "=v"(v.u[2]) : "v"(hi[0]), "v"(hi[1]));
  asm("v_cvt_pk_bf16_f32 %0, %1, %2" : "=v"(v.u[3]) : "v"(hi[2]), "v"(hi[3]));
  return v.s;
}

template <typename T>
__device__ __forceinline__ void load_lds16(const T* g, T* l) {
  __builtin_amdgcn_global_load_lds((const __attribute__((address_space(1))) unsigned*)g,
                                   (__attribute__((address_space(3))) unsigned*)l, 16, 0, 0);
}

constexpr int TB = 4;       // batch
constexpr int TT = 4096;    // seq len
constexpr int DM = 1024;    // d_model
constexpr int DD = 128;     // head dim
constexpr int NE = 384;     // 3*DD
constexpr int NSPLIT = 4;   // flash-decode KV split
constexpr int CHUNK = TT / NSPLIT;  // 1024
constexpr float QSCALE = 0.12751744f;  // 128^-0.5 * log2(e)

// ---------------- kernel 0: W transpose + bf16 cast ----------------
__global__ void wtrans_kernel(const float* __restrict__ W, unsigned short* __restrict__ Wt) {
  int i = blockIdx.x * 256 + threadIdx.x;   // 0 .. 1024*384-1
  int k = i / NE, n = i - k * NE;
  Wt[n * DM + k] = bf16r(W[i]);
}

// ---------------- kernel 1: QKV projection (64x128 tile, BK=32, dbuf) ------
// grid 768 blocks (3/CU). LDS XOR-swizzled; global_load_lds with pre-swizzled
// per-lane SOURCE addresses (LDS dest stays linear) per m173.
__global__ __launch_bounds__(256, 4)
void qkv_kernel(const float* __restrict__ x, const unsigned short* __restrict__ Wt,
                const float* __restrict__ bq,
                unsigned short* __restrict__ Qb, unsigned short* __restrict__ Kb,
                unsigned short* __restrict__ Vt) {
  const int tid = threadIdx.x;
  const int wid = tid >> 6, lane = tid & 63;
  const int g = lane >> 4, c = lane & 15;
  const int wr = wid >> 1, wc = wid & 1;
  const int m0 = blockIdx.x * 64;
  const int n0 = blockIdx.y * 128;

  __shared__ float          As[2][2048];   // [64 rows][32 k] fp32, 8KB per buf
  __shared__ unsigned short Bs[2][4096];   // [128 cols][32 k] bf16, 8KB per buf

  f32x4 acc[2][4];
  #pragma unroll
  for (int m = 0; m < 2; ++m)
    #pragma unroll
    for (int n = 0; n < 4; ++n) acc[m][n] = f32x4{0.f, 0.f, 0.f, 0.f};

  // per-thread staging geometry (source pre-swizzled, dest linear by unit L)
#define QKV_STAGE(buf, kb) do {                                                  \
    _Pragma("unroll")                                                            \
    for (int i_ = 0; i_ < 2; ++i_) {                                             \
      int L = i_ * 256 + tid, ar = L >> 3, au = (L & 7) ^ (ar & 7);              \
      load_lds16(x + (size_t)(m0 + ar) * DM + (kb) * 32 + au * 4,                \
                 &As[buf][L * 4]);                                               \
    }                                                                            \
    _Pragma("unroll")                                                            \
    for (int i_ = 0; i_ < 2; ++i_) {                                             \
      int L = i_ * 256 + tid, br = L >> 2, bu = (L & 3) ^ (br & 3);              \
      load_lds16(Wt + (size_t)(n0 + br) * DM + (kb) * 32 + bu * 8,               \
                 &Bs[buf][L * 8]);                                               \
    }                                                                            \
  } while (0)

  QKV_STAGE(0, 0);
  __syncthreads();

  const int cx7 = (c & 7) << 4, cx3 = (c & 3) << 4;
  for (int kb = 0; kb < DM / 32; ++kb) {
    const int cur = kb & 1;
    if (kb + 1 < DM / 32) QKV_STAGE(cur ^ 1, kb + 1);

    short8 a[2], b[4];
    #pragma unroll
    for (int m = 0; m < 2; ++m) {
      int row = wr * 32 + m * 16 + c;
      f32x4 lo = *(const f32x4*)((const char*)&As[cur][0] + row * 128 + ((g * 32)      ^ cx7));
      f32x4 hi = *(const f32x4*)((const char*)&As[cur][0] + row * 128 + ((g * 32 + 16) ^ cx7));
      a[m] = cvt8(lo, hi);
    }
    #pragma unroll
    for (int n = 0; n < 4; ++n) {
      int row = wc * 64 + n * 16 + c;
      b[n] = *(const short8*)((const char*)&Bs[cur][0] + row * 64 + ((g * 16) ^ cx3));
    }

    __builtin_amdgcn_s_setprio(1);
    #pragma unroll
    for (int m = 0; m < 2; ++m)
      #pragma unroll
      for (int n = 0; n < 4; ++n)
        acc[m][n] = MFMA16(a[m], b[n], acc[m][n]);
    __builtin_amdgcn_s_setprio(0);

    __syncthreads();
  }

  // epilogue: bias + de-interleave (col e%3: 0->Q(scaled), 1->K, 2->V^T)
  #pragma unroll
  for (int n = 0; n < 4; ++n) {
    int e = n0 + wc * 64 + n * 16 + c;
    float bias = bq[e];
    int n3 = e % 3, d = e / 3;
    #pragma unroll
    for (int m = 0; m < 2; ++m) {
      #pragma unroll
      for (int r = 0; r < 4; ++r) {
        int row = m0 + wr * 32 + m * 16 + g * 4 + r;   // C/D: row=(l>>4)*4+r
        float val = acc[m][n][r] + bias;
        int bb = row >> 12, tr = row & (TT - 1);
        if (n3 == 0)      Qb[row * DD + d] = bf16r(val * QSCALE);
        else if (n3 == 1) Kb[row * DD + d] = bf16r(val);
        else              Vt[(bb * DD + d) * TT + tr] = bf16r(val);
      }
    }
  }
#undef QKV_STAGE
}

// ---------------- kernel 2: flash attention (QBLK=32/wave, XOR-swizzled LDS) ----
constexpr int KVB = 64;
__global__ __launch_bounds__(256, 2)
void attn_kernel(const unsigned short* __restrict__ Qb, const unsigned short* __restrict__ Kb,
                 const unsigned short* __restrict__ Vt,
                 float* __restrict__ Opart, float* __restrict__ Mpart, float* __restrict__ Lpart) {
  const int tid = threadIdx.x;
  const int wid = tid >> 6, lane = tid & 63;
  const int g = lane >> 4, c = lane & 15;
  const int b = blockIdx.y;
  const int z = blockIdx.z;
  const int qw = blockIdx.x * 128 + wid * 32;   // wave's 32 q-rows
  const int s_base = z * CHUNK;

  __shared__ __align__(16) unsigned char KtS[KVB * 256];     // [64 keys][128 d] bf16, 16KB
  __shared__ __align__(16) unsigned char VtS[128 * 128];     // [128 d][64 keys] bf16, 16KB
  __shared__ __align__(16) unsigned char PlS[4][32 * 128];   // per-wave [32 q][64 keys], 16KB

  const int cx = (c & 7) << 4;     // read-side XOR

  // Q fragments (2 groups x 4 k-slots), pre-scaled by QSCALE at qkv time
  short8 qf[2][4];
  #pragma unroll
  for (int grp = 0; grp < 2; ++grp) {
    const unsigned short* qrow = Qb + (size_t)(b * TT + qw + grp * 16 + c) * DD + g * 8;
    #pragma unroll
    for (int kk = 0; kk < 4; ++kk) qf[grp][kk] = *(const short8*)(qrow + kk * 32);
  }

  short8 onesb;           // bf16 1.0 x8 : PV ones-column computes row-sum l via MFMA
  #pragma unroll
  for (int j = 0; j < 8; ++j) onesb[j] = (short)0x3F80;

  float mr[2][4];
  f32x4 lacc[2];
  f32x4 oacc[2][8];
  #pragma unroll
  for (int grp = 0; grp < 2; ++grp) {
    #pragma unroll
    for (int r = 0; r < 4; ++r) mr[grp][r] = -1e30f;
    lacc[grp] = f32x4{0.f, 0.f, 0.f, 0.f};
    #pragma unroll
    for (int n = 0; n < 8; ++n) oacc[grp][n] = f32x4{0.f, 0.f, 0.f, 0.f};
  }

  // staging geometry (reg-staged; LDS writes XOR-swizzled)
  short8 kreg[4], vreg[4];
  const int krow_ = tid >> 4;                                 // 0..15
  const int kgcol = (tid & 15) * 8;                           // global col (elements)
  const int kwb   = ((tid & 15) * 16) ^ ((krow_ & 7) << 4);   // lds byte-in-row
  const int vrow_ = tid >> 3;                                 // 0..31
  const int vgcol = (tid & 7) * 8;
  const int vwb   = ((tid & 7) * 16) ^ ((vrow_ & 7) << 4);

  const unsigned short* Kbase = Kb + (size_t)(b * TT) * DD;
  const unsigned short* Vbase = Vt + (size_t)(b * DD) * TT;

  #pragma unroll
  for (int p = 0; p < 4; ++p) {
    kreg[p] = *(const short8*)(Kbase + (size_t)(s_base + p * 16 + krow_) * DD + kgcol);
    vreg[p] = *(const short8*)(Vbase + (size_t)(p * 32 + vrow_) * TT + s_base + vgcol);
  }
  #pragma unroll
  for (int p = 0; p < 4; ++p) {
    *(short8*)(KtS + (p * 16 + krow_) * 256 + kwb) = kreg[p];
    *(short8*)(VtS + (p * 32 + vrow_) * 128 + vwb) = vreg[p];
  }
  __syncthreads();

  const int NT = CHUNK / KVB;   // 16
  for (int it = 0; it < NT; ++it) {
    if (it + 1 < NT) {
      int s0 = s_base + (it + 1) * KVB;
      #pragma unroll
      for (int p = 0; p < 4; ++p) {
        kreg[p] = *(const short8*)(Kbase + (size_t)(s0 + p * 16 + krow_) * DD + kgcol);
        vreg[p] = *(const short8*)(Vbase + (size_t)(p * 32 + vrow_) * TT + s0 + vgcol);
      }
    }

    // QK^T: S[32 q][64 keys] per wave; kf shared across both q-groups
    f32x4 sacc[2][4];
    #pragma unroll
    for (int grp = 0; grp < 2; ++grp)
      #pragma unroll
      for (int t = 0; t < 4; ++t) sacc[grp][t] = f32x4{0.f, 0.f, 0.f, 0.f};
    __builtin_amdgcn_s_setprio(1);
    #pragma unroll
    for (int kk = 0; kk < 4; ++kk) {
      #pragma unroll
      for (int t = 0; t < 4; ++t) {
        short8 kf = *(const short8*)(KtS + (t * 16 + c) * 256 + ((kk * 64 + g * 16) ^ cx));
        sacc[0][t] = MFMA16(qf[0][kk], kf, sacc[0][t]);
        sacc[1][t] = MFMA16(qf[1][kk], kf, sacc[1][t]);
      }
    }
    __builtin_amdgcn_s_setprio(0);

    // online softmax (log2 domain), per group; row-sum via PV ones-column MFMA
    #pragma unroll
    for (int grp = 0; grp < 2; ++grp) {
      float pe[4][4];
      #pragma unroll
      for (int r = 0; r < 4; ++r) {
        float mx = fmaxf(fmaxf(sacc[grp][0][r], sacc[grp][1][r]),
                         fmaxf(sacc[grp][2][r], sacc[grp][3][r]));
        mx = fmaxf(mx, __shfl_xor(mx, 1));
        mx = fmaxf(mx, __shfl_xor(mx, 2));
        mx = fmaxf(mx, __shfl_xor(mx, 4));
        mx = fmaxf(mx, __shfl_xor(mx, 8));
        float mnew = fmaxf(mr[grp][r], mx);
        float alpha = exp2f(mr[grp][r] - mnew);
        mr[grp][r] = mnew;
        #pragma unroll
        for (int t = 0; t < 4; ++t) pe[t][r] = exp2f(sacc[grp][t][r] - mnew);
        lacc[grp][r] *= alpha;
        #pragma unroll
        for (int n = 0; n < 8; ++n) oacc[grp][n][r] *= alpha;
      }
      // P -> per-wave LDS (swizzled scalar writes; wave-synchronous)
      #pragma unroll
      for (int t = 0; t < 4; ++t)
        #pragma unroll
        for (int r = 0; r < 4; ++r) {
          int prow = grp * 16 + g * 4 + r;
          *(unsigned short*)(PlS[wid] + prow * 128 + ((t * 32 + c * 2) ^ (((g * 4 + r) & 7) << 4)))
              = bf16r(pe[t][r]);
        }
    }

    // PV: O[32 q][128 d] += P[32][64] @ V[64][128]; vf shared across groups
    __builtin_amdgcn_s_setprio(1);
    #pragma unroll
    for (int ks = 0; ks < 2; ++ks) {
      short8 pf0 = *(const short8*)(PlS[wid] + (c) * 128      + ((ks * 64 + g * 16) ^ cx));
      short8 pf1 = *(const short8*)(PlS[wid] + (16 + c) * 128 + ((ks * 64 + g * 16) ^ cx));
      lacc[0] = MFMA16(pf0, onesb, lacc[0]);
      lacc[1] = MFMA16(pf1, onesb, lacc[1]);
      #pragma unroll
      for (int n = 0; n < 8; ++n) {
        short8 vf = *(const short8*)(VtS + (n * 16 + c) * 128 + ((ks * 64 + g * 16) ^ cx));
        oacc[0][n] = MFMA16(pf0, vf, oacc[0][n]);
        oacc[1][n] = MFMA16(pf1, vf, oacc[1][n]);
      }
    }
    __builtin_amdgcn_s_setprio(0);

    __syncthreads();
    if (it + 1 < NT) {
      #pragma unroll
      for (int p = 0; p < 4; ++p) {
        *(short8*)(KtS + (p * 16 + krow_) * 256 + kwb) = kreg[p];
        *(short8*)(VtS + (p * 32 + vrow_) * 128 + vwb) = vreg[p];
      }
    }
    __syncthreads();
  }

  const size_t pbase = (size_t)(z * TB + b) * TT;
  #pragma unroll
  for (int grp = 0; grp < 2; ++grp) {
    #pragma unroll
    for (int n = 0; n < 8; ++n)
      #pragma unroll
      for (int r = 0; r < 4; ++r) {
        int row = qw + grp * 16 + g * 4 + r;
        Opart[(pbase + row) * DD + n * 16 + c] = oacc[grp][n][r];
      }
    if (c == 0) {
      #pragma unroll
      for (int r = 0; r < 4; ++r) {
        int row = qw + grp * 16 + g * 4 + r;
        Mpart[pbase + row] = mr[grp][r];
        Lpart[pbase + row] = lacc[grp][r];
      }
    }
  }
}

// ---------------- kernel 3: split merge ----------------
__global__ void merge_kernel(const float* __restrict__ Opart, const float* __restrict__ Mpart,
                             const float* __restrict__ Lpart, float* __restrict__ out) {
  int i = blockIdx.x * 256 + threadIdx.x;   // 0 .. 16384*32-1
  int grow = i >> 5, d4 = (i & 31) << 2;
  float m[NSPLIT];
  float ms = -1e30f;
  #pragma unroll
  for (int s = 0; s < NSPLIT; ++s) { m[s] = Mpart[s * (TB * TT) + grow]; ms = fmaxf(ms, m[s]); }
  float w[NSPLIT];
  float denom = 0.f;
  #pragma unroll
  for (int s = 0; s < NSPLIT; ++s) {
    w[s] = exp2f(m[s] - ms);
    denom += w[s] * Lpart[s * (TB * TT) + grow];
  }
  float rd = 1.0f / denom;
  f32x4 o = {0.f, 0.f, 0.f, 0.f};
  #pragma unroll
  for (int s = 0; s < NSPLIT; ++s) {
    f32x4 v = *(const f32x4*)(Opart + (size_t)(s * (TB * TT) + grow) * DD + d4);
    o += v * w[s];
  }
  *(f32x4*)(out + (size_t)grow * DD + d4) = o * rd;
}

extern "C" void kernel_launch(void* const* d_in, const int* in_sizes, int n_in,
                              void* d_out, int out_size, void* d_ws, size_t ws_size,
                              hipStream_t stream) {
  const float* x  = (const float*)d_in[0];   // [4,4096,1024]
  const float* W  = (const float*)d_in[1];   // [1024,384]
  const float* bq = (const float*)d_in[2];   // [384]
  float* out = (float*)d_out;                // [4,4096,128] f32

  unsigned char* ws = (unsigned char*)d_ws;
  unsigned short* Qb = (unsigned short*)(ws);                  // 4 MB bf16 (scaled)
  unsigned short* Kb = (unsigned short*)(ws + (4u  << 20));    // 4 MB bf16
  unsigned short* Vt = (unsigned short*)(ws + (8u  << 20));    // 4 MB bf16 (V^T)
  unsigned short* Wt = (unsigned short*)(ws + (12u << 20));    // 768 KB bf16
  float* Mpart = (float*)(ws + (13u << 20));                   // 256 KB
  float* Lpart = (float*)(ws + (14u << 20));                   // 256 KB
  float* Opart = (float*)(ws + (16u << 20));                   // 32 MB

  wtrans_kernel<<<(DM * NE) / 256, 256, 0, stream>>>(W, Wt);
  qkv_kernel<<<dim3(TB * TT / 64, NE / 128), 256, 0, stream>>>(x, Wt, bq, Qb, Kb, Vt);
  attn_kernel<<<dim3(TT / 128, TB, NSPLIT), 256, 0, stream>>>(Qb, Kb, Vt, Opart, Mpart, Lpart);
  merge_kernel<<<(TB * TT * 32) / 256, 256, 0, stream>>>(Opart, Mpart, Lpart, out);
}